// Round 1
// baseline (307.419 us; speedup 1.0000x reference)
//
#include <hip/hip_runtime.h>
#include <stdint.h>

typedef unsigned long long u64;

#define K_MSG   1024
#define N_CODE  2048
#define NB      32768
#define KW      16        // 1024 bits / 64 = 16 u64 words per row/col
#define ROWS_TILE 256
#define COLS_TILE 64

// ---------------- pack b: [NB][K_MSG] int32 -> [NB][KW] u64 ----------------
// word index w in row i: bit l = b[i][w*64 + l].  Linear: addr = word*64 + lane.
__global__ void pack_b_kernel(const int* __restrict__ b, u64* __restrict__ bp,
                              int nwords) {
    const int lane  = threadIdx.x & 63;
    const int wave  = blockIdx.x * (blockDim.x >> 6) + (threadIdx.x >> 6);
    const int nwave = gridDim.x * (blockDim.x >> 6);
    for (int word = wave; word < nwords; word += nwave) {
        int v = b[(size_t)word * 64 + lane];
        u64 m = __ballot((v & 1) != 0);
        if (lane == 0) bp[word] = m;
    }
}

// ---------------- pack G: [K_MSG][N_CODE] int32 -> Gp[w][j] u64 -------------
// Gp[w*N_CODE + j]: bit t = G[w*64 + t][j].  One wave per (w, 64-col group).
__global__ void pack_g_kernel(const int* __restrict__ G, u64* __restrict__ gp) {
    const int lane = threadIdx.x & 63;
    const int wave = blockIdx.x * (blockDim.x >> 6) + (threadIdx.x >> 6); // 0..511
    const int w    = wave >> 5;   // 0..15
    const int jb   = wave & 31;   // 0..31
    const int j    = jb * 64 + lane;
    u64 word = 0;
#pragma unroll 16
    for (int t = 0; t < 64; ++t) {
        int v = G[(size_t)(w * 64 + t) * N_CODE + j];
        word |= (u64)(v & 1) << t;
    }
    gp[(size_t)w * N_CODE + j] = word;
}

// ---------------- main: c[i][j] = parity(popc(bp_row & gp_col)) -------------
// Block: 256 thr = 4 waves. blockIdx.x -> 64-col tile (lane = column),
// blockIdx.y -> 256-row tile; wave ty handles rows ty, ty+4, ...
// bp row address is wave-uniform -> scalar loads; gp held in 32 VGPRs.
__global__ __launch_bounds__(256) void encode_main(const u64* __restrict__ bp,
                                                   const u64* __restrict__ gp,
                                                   int* __restrict__ out) {
    const int tx = threadIdx.x & 63;
    const int ty = threadIdx.x >> 6;
    const int j  = blockIdx.x * COLS_TILE + tx;
    const int r0 = blockIdx.y * ROWS_TILE;

    u64 g[KW];
#pragma unroll
    for (int w = 0; w < KW; ++w) g[w] = gp[(size_t)w * N_CODE + j];

    int* outp = out + (size_t)r0 * N_CODE + j;

#pragma unroll 2
    for (int rr = ty; rr < ROWS_TILE; rr += 4) {
        const u64* __restrict__ row = bp + ((size_t)(r0 + rr) << 4);
        u64 a0 = (row[0]  & g[0])  ^ (row[1]  & g[1]);
        u64 a1 = (row[2]  & g[2])  ^ (row[3]  & g[3]);
        u64 a2 = (row[4]  & g[4])  ^ (row[5]  & g[5]);
        u64 a3 = (row[6]  & g[6])  ^ (row[7]  & g[7]);
        u64 a4 = (row[8]  & g[8])  ^ (row[9]  & g[9]);
        u64 a5 = (row[10] & g[10]) ^ (row[11] & g[11]);
        u64 a6 = (row[12] & g[12]) ^ (row[13] & g[13]);
        u64 a7 = (row[14] & g[14]) ^ (row[15] & g[15]);
        u64 acc = ((a0 ^ a1) ^ (a2 ^ a3)) ^ ((a4 ^ a5) ^ (a6 ^ a7));
        unsigned x = (unsigned)acc ^ (unsigned)(acc >> 32);
        outp[(size_t)rr * N_CODE] = (int)(__popc(x) & 1);
    }
}

// ---------------- fallback (only if ws too small; correct but slow) ---------
__global__ void encode_naive(const int* __restrict__ b, const int* __restrict__ G,
                             int* __restrict__ out) {
    size_t idx = (size_t)blockIdx.x * blockDim.x + threadIdx.x;
    size_t total = (size_t)NB * N_CODE;
    if (idx >= total) return;
    int i = (int)(idx / N_CODE);
    int j = (int)(idx % N_CODE);
    int acc = 0;
    for (int k = 0; k < K_MSG; ++k)
        acc ^= b[(size_t)i * K_MSG + k] & G[(size_t)k * N_CODE + j];
    out[idx] = acc & 1;
}

extern "C" void kernel_launch(void* const* d_in, const int* in_sizes, int n_in,
                              void* d_out, int out_size, void* d_ws, size_t ws_size,
                              hipStream_t stream) {
    const int* b = (const int*)d_in[0];
    const int* G = (const int*)d_in[1];
    int* out = (int*)d_out;

    const size_t bp_bytes = (size_t)NB * KW * sizeof(u64);      // 4 MiB
    const size_t gp_bytes = (size_t)N_CODE * KW * sizeof(u64);  // 256 KiB

    if (ws_size < bp_bytes + gp_bytes) {
        size_t total = (size_t)NB * N_CODE;
        encode_naive<<<(unsigned)((total + 255) / 256), 256, 0, stream>>>(b, G, out);
        return;
    }

    u64* bp = (u64*)d_ws;
    u64* gp = (u64*)((char*)d_ws + bp_bytes);

    pack_b_kernel<<<2048, 256, 0, stream>>>(b, bp, NB * KW);
    pack_g_kernel<<<128, 256, 0, stream>>>(G, gp);

    dim3 grid(N_CODE / COLS_TILE, NB / ROWS_TILE);  // 32 x 128
    encode_main<<<grid, 256, 0, stream>>>(bp, gp, out);
}